// Round 13
// baseline (515.772 us; speedup 1.0000x reference)
//
#include <hip/hip_runtime.h>
#include <hip/hip_bf16.h>

#define NN 100000
#define EE 1600000
#define GG 256
#define SLOPE 0.01f
#define CAP 48      // bucket capacity; deg~Poisson(16), P(deg>48) ~ 1e-13
#define PPART 8     // dst partitions for build == number of XCDs
#define NPART (NN / PPART)   // 12500 nodes per partition
#define BPP 250              // blocks per partition
#define EPB (EE / BPP)       // 6400 edges per block (exact)

typedef __hip_bfloat16 bf16;
typedef __attribute__((ext_vector_type(8))) short s16x8;
typedef __attribute__((ext_vector_type(4))) float f32x4;

__device__ __forceinline__ float leaky(float x) { return x > 0.f ? x : SLOPE * x; }
__device__ __forceinline__ float bf2f(bf16 v) { return __bfloat162float(v); }
__device__ __forceinline__ float bf_lo(unsigned v) { return __uint_as_float(v << 16); }
__device__ __forceinline__ float bf_hi(unsigned v) { return __uint_as_float(v & 0xFFFF0000u); }

// pack: src (17b) | bf16-weight-sans-sign (15b). w >= 0 always (uniform[0,1)).
__device__ __forceinline__ unsigned pack_pair(int s, float w) {
    unsigned u = __float_as_uint(w);
    u += 0x7FFFu + ((u >> 16) & 1u);  // RNE to bf16
    return ((unsigned)s << 15) | ((u >> 16) & 0x7FFFu);
}
__device__ __forceinline__ int pair_src(unsigned v) { return (int)(v >> 15); }
__device__ __forceinline__ float pair_w(unsigned v) {
    return __uint_as_float((v & 0x7FFFu) << 16);
}

// ---------- dst-partitioned bucket-CSR build, partition pinned to XCD ----------
// partition = blockIdx % 8 pins each partition to ONE XCD (round-robin dispatch);
// nontemporal edge reads keep the 74 MB stream from evicting dirty bucket lines.
__global__ __launch_bounds__(256) void build_bucket(const int* __restrict__ src,
                                                    const int* __restrict__ dst,
                                                    const float* __restrict__ ew,
                                                    int* __restrict__ cnt,
                                                    unsigned* __restrict__ pairs) {
    int part = blockIdx.x % PPART;   // XCD-aligned partition
    int blk = blockIdx.x / PPART;
    int lo = part * NPART, hi = lo + NPART;
    int start = blk * EPB;  // EPB = 25 * 256 exactly
#pragma unroll
    for (int jb = 0; jb < 5; jb++) {
        int e[5], d[5];
#pragma unroll
        for (int j = 0; j < 5; j++) {
            e[j] = start + (jb * 5 + j) * 256 + threadIdx.x;
            d[j] = __builtin_nontemporal_load(&dst[e[j]]);
        }
#pragma unroll
        for (int j = 0; j < 5; j++) {
            if (d[j] >= lo && d[j] < hi) {
                int s = __builtin_nontemporal_load(&src[e[j]]);
                float w = __builtin_nontemporal_load(&ew[e[j]]);
                int pos = atomicAdd(&cnt[d[j]], 1);
                if (pos < CAP) pairs[d[j] * CAP + pos] = pack_pair(s, w);
            }
        }
    }
}

// ---------- per-node factors + y0 = dis * X (no atomics) ----------
__global__ void node_fac(const int* __restrict__ cnt, const unsigned* __restrict__ pairs,
                         const float* __restrict__ X, float* __restrict__ dis,
                         float* __restrict__ selfn, float* __restrict__ rdis,
                         float* __restrict__ y0) {
    int n = blockIdx.x * blockDim.x + threadIdx.x;
    if (n >= NN) return;
    int len = min(cnt[n], CAP);
    float deg = 1.0f;  // self-loop weight
    const unsigned* row = pairs + n * CAP;
    for (int i = 0; i < len; i++) deg += pair_w(row[i]);
    float r = rsqrtf(deg);
    dis[n] = r;
    selfn[n] = r * r;       // 1/deg
    rdis[n] = deg * r;      // sqrt(deg) = 1/dis
    y0[n * 3 + 0] = r * X[n * 3 + 0];
    y0[n * 3 + 1] = r * X[n * 3 + 1];
    y0[n * 3 + 2] = r * X[n * 3 + 2];
}

// ---------- propagation F=3 in y-space: y' = selfn*(y[n] + sum w*y[src]) ----------
__global__ void gather3_kernel(const int* __restrict__ cnt, const unsigned* __restrict__ pairs,
                               const float* __restrict__ selfn, const float* __restrict__ yin,
                               float* __restrict__ yout) {
    int n = blockIdx.x * blockDim.x + threadIdx.x;
    if (n >= NN) return;
    int len = min(cnt[n], CAP);
    const unsigned* row = pairs + n * CAP;
    float a0 = yin[n * 3 + 0], a1 = yin[n * 3 + 1], a2 = yin[n * 3 + 2];
    for (int i = 0; i < len; i++) {
        unsigned v = __builtin_nontemporal_load(&row[i]);
        int s3 = pair_src(v) * 3;
        float w = pair_w(v);
        a0 += w * yin[s3 + 0];
        a1 += w * yin[s3 + 1];
        a2 += w * yin[s3 + 2];
    }
    float sv = selfn[n];
    yout[n * 3 + 0] = sv * a0;
    yout[n * 3 + 1] = sv * a1;
    yout[n * 3 + 2] = sv * a2;
}

// ---------- propagation F=64, 2 nodes per wave (32 lanes x bf16x2 per row) ----------
// pairs/cnt reads nontemporal: read-once streams must not evict the y-table from L2.
__global__ __launch_bounds__(256) void gather64b_kernel(const int* __restrict__ cnt,
                                                        const unsigned* __restrict__ pairs,
                                                        const float* __restrict__ selfn,
                                                        const bf16* __restrict__ yin,
                                                        bf16* __restrict__ yout) {
    int wv = (int)((blockIdx.x * (unsigned)blockDim.x + threadIdx.x) >> 6);
    int lane = threadIdx.x & 63;
    int half = lane >> 5, sub = lane & 31;
    int node = wv * 2 + half;
    if (node >= NN) return;
    int len = min(__builtin_nontemporal_load(&cnt[node]), CAP);
    const unsigned* row = pairs + node * CAP;
    const unsigned* ybase = (const unsigned*)yin;  // 2 bf16 per word, 32 words per row
    unsigned svv = ybase[node * 32 + sub];
    float a0 = bf_lo(svv), a1 = bf_hi(svv);  // self edge, weight 1
    int i = 0;
    for (; i + 7 < len; i += 8) {
        unsigned pv[8], gv[8];
#pragma unroll
        for (int j = 0; j < 8; j++) pv[j] = __builtin_nontemporal_load(&row[i + j]);
#pragma unroll
        for (int j = 0; j < 8; j++) gv[j] = ybase[pair_src(pv[j]) * 32 + sub];
#pragma unroll
        for (int j = 0; j < 8; j++) {
            float w = pair_w(pv[j]);
            a0 += w * bf_lo(gv[j]);
            a1 += w * bf_hi(gv[j]);
        }
    }
    for (; i < len; i++) {
        unsigned v = __builtin_nontemporal_load(&row[i]);
        unsigned g = ybase[pair_src(v) * 32 + sub];
        float w = pair_w(v);
        a0 += w * bf_lo(g);
        a1 += w * bf_hi(g);
    }
    float s = selfn[node];
    bf16 b0 = __float2bfloat16(a0 * s), b1 = __float2bfloat16(a1 * s);
    unsigned o = ((unsigned)*(unsigned short*)&b1 << 16) | *(unsigned short*)&b0;
    ((unsigned*)yout)[node * 32 + sub] = o;
}

// ---------- layer 1 output: h = leaky(rdis*sum_k y_k@W_k + b); store dis*h (y-space) ----------
__global__ __launch_bounds__(256) void l1_out(const float* __restrict__ y0, const float* __restrict__ y1,
                                              const float* __restrict__ y2, const float* __restrict__ y3,
                                              const float* __restrict__ w, const float* __restrict__ b,
                                              const float* __restrict__ rdis, const float* __restrict__ dis,
                                              bf16* __restrict__ h) {
    __shared__ float wl[4 * 3 * 64];
    __shared__ float bl[64];
    for (int t = threadIdx.x; t < 768; t += 256) wl[t] = w[t];
    if (threadIdx.x < 64) bl[threadIdx.x] = b[threadIdx.x];
    __syncthreads();
    int lane = threadIdx.x & 63;
    int nodeBase = blockIdx.x * 32 + (threadIdx.x >> 6) * 8;  // N = 3125*32 exactly
    const float* ys[4] = {y0, y1, y2, y3};
#pragma unroll
    for (int r = 0; r < 8; r++) {
        int node = nodeBase + r;
        float acc = 0.f;
#pragma unroll
        for (int k = 0; k < 4; k++) {
            const float* yp = ys[k] + node * 3;
            acc += yp[0] * wl[k * 192 + lane] + yp[1] * wl[k * 192 + 64 + lane] +
                   yp[2] * wl[k * 192 + 128 + lane];
        }
        float hv = leaky(rdis[node] * acc + bl[lane]);
        h[node * 64 + lane] = __float2bfloat16(dis[node] * hv);  // y-space for layer 2
    }
}

// ---------- layer 2 via MFMA (16x16x32 bf16, K=256, N=64), y-space in, x-space out ----
// A-frag: lane l holds A[l&15][(l>>4)*8 + j]; B-frag: lane l holds B[(l>>4)*8+j][l&15].
// C/D (verified m89): col = lane&15, row = (lane>>4)*4 + reg.
__global__ __launch_bounds__(256) void l2_mfma(const bf16* __restrict__ h0, const bf16* __restrict__ h1,
                                               const bf16* __restrict__ h2, const bf16* __restrict__ h3,
                                               const float* __restrict__ w, const float* __restrict__ b,
                                               const float* __restrict__ rdis, float* __restrict__ out) {
    __shared__ bf16 bt[64 * 256];  // BT[n][k], XOR-swizzled, 32 KiB
    __shared__ float bl[64];
    char* btc = (char*)bt;
    for (int idx = threadIdx.x; idx < 16384; idx += 256) {
        int k = idx >> 6, n = idx & 63;  // k = hop*64 + j (row-major w)
        bf16 v = __float2bfloat16(w[idx]);
        *(bf16*)(btc + n * 512 + ((k * 2) ^ ((n & 7) << 4))) = v;
    }
    if (threadIdx.x < 64) bl[threadIdx.x] = b[threadIdx.x];
    __syncthreads();

    int lane = threadIdx.x & 63;
    int rbase = blockIdx.x * 64 + (threadIdx.x >> 6) * 16;  // wave's 16-row tile
    if (rbase >= NN) return;
    const bf16* hs[4] = {h0, h1, h2, h3};

    f32x4 acc0 = {0.f, 0.f, 0.f, 0.f}, acc1 = acc0, acc2 = acc0, acc3 = acc0;
    int arow = rbase + (lane & 15);
    int kgrp = (lane >> 4) * 8;
#pragma unroll
    for (int ks = 0; ks < 8; ks++) {
        const bf16* hp = hs[ks >> 1];
        s16x8 a = *(const s16x8*)(hp + arow * 64 + (ks & 1) * 32 + kgrp);
        int kbyte = ks * 64 + kgrp * 2;
#pragma unroll
        for (int t = 0; t < 4; t++) {
            int n = t * 16 + (lane & 15);
            s16x8 bb = *(const s16x8*)(btc + n * 512 + (kbyte ^ ((n & 7) << 4)));
            f32x4* ap = (t == 0) ? &acc0 : (t == 1) ? &acc1 : (t == 2) ? &acc2 : &acc3;
            *ap = __builtin_amdgcn_mfma_f32_16x16x32_bf16(a, bb, *ap, 0, 0, 0);
        }
    }
    int col = lane & 15, rgrp = (lane >> 4) * 4;
#pragma unroll
    for (int t = 0; t < 4; t++) {
        f32x4 a = (t == 0) ? acc0 : (t == 1) ? acc1 : (t == 2) ? acc2 : acc3;
        float bias = bl[t * 16 + col];
#pragma unroll
        for (int r = 0; r < 4; r++) {
            int rowi = rbase + rgrp + r;
            out[(size_t)rowi * 64 + t * 16 + col] = leaky(rdis[rowi] * a[r] + bias);
        }
    }
}

// ---------- pooling (Batching is sorted) ----------
#define PWAVES 2048
#define NPW ((NN + PWAVES - 1) / PWAVES)  // 49
__global__ void pool_kernel(const float* __restrict__ h, const int* __restrict__ batching,
                            float* __restrict__ pooled, float* __restrict__ cnt) {
    int wid = (int)((blockIdx.x * (unsigned)blockDim.x + threadIdx.x) >> 6);
    int lane = threadIdx.x & 63;
    int start = wid * NPW;
    if (start >= NN) return;
    int end = min(start + NPW, NN);
    int g = batching[start];
    float acc = 0.f, c = 0.f;
    for (int i = start; i < end; i++) {
        int gi = batching[i];
        if (gi != g) {
            atomicAdd(&pooled[g * 64 + lane], acc);
            if (lane == 0) atomicAdd(&cnt[g], c);
            g = gi; acc = 0.f; c = 0.f;
        }
        acc += h[(size_t)i * 64 + lane];
        c += 1.f;
    }
    atomicAdd(&pooled[g * 64 + lane], acc);
    if (lane == 0) atomicAdd(&cnt[g], c);
}

// ---------- heads: two 64->64->64->2 MLPs per graph ----------
__global__ void head_kernel(const float* __restrict__ pooled, const float* __restrict__ cnt,
                            const float* pw1, const float* pb1, const float* pw2, const float* pb2,
                            const float* pw3, const float* pb3,
                            const float* tw1, const float* tb1, const float* tw2, const float* tb2,
                            const float* tw3, const float* tb3,
                            float* __restrict__ out) {
    int g = blockIdx.x, f = threadIdx.x;  // 64 threads
    __shared__ float pm[64], t1[64], t2[64];
    float c = cnt[g];
    if (c < 1.f) c = 1.f;
    pm[f] = pooled[g * 64 + f] / c;
    __syncthreads();
    float a = pb1[f];
    for (int j = 0; j < 64; j++) a += pm[j] * pw1[j * 64 + f];
    t1[f] = leaky(a);
    __syncthreads();
    a = pb2[f];
    for (int j = 0; j < 64; j++) a += t1[j] * pw2[j * 64 + f];
    t2[f] = leaky(a);
    __syncthreads();
    if (f < 2) {
        float o = pb3[f];
        for (int j = 0; j < 64; j++) o += t2[j] * pw3[j * 2 + f];
        out[g * 4 + f] = o;
    }
    __syncthreads();
    a = tb1[f];
    for (int j = 0; j < 64; j++) a += pm[j] * tw1[j * 64 + f];
    t1[f] = leaky(a);
    __syncthreads();
    a = tb2[f];
    for (int j = 0; j < 64; j++) a += t1[j] * tw2[j * 64 + f];
    t2[f] = leaky(a);
    __syncthreads();
    if (f < 2) {
        float o = tb3[f];
        for (int j = 0; j < 64; j++) o += t2[j] * tw3[j * 2 + f];
        out[g * 4 + 2 + f] = o;
    }
}

extern "C" void kernel_launch(void* const* d_in, const int* in_sizes, int n_in,
                              void* d_out, int out_size, void* d_ws, size_t ws_size,
                              hipStream_t stream) {
    const float* X = (const float*)d_in[0];
    const int* ei = (const int*)d_in[1];  // [2][E]
    const float* ew = (const float*)d_in[2];
    const int* batching = (const int*)d_in[3];
    const float* c1w = (const float*)d_in[4];
    const float* c1b = (const float*)d_in[5];
    const float* c2w = (const float*)d_in[6];
    const float* c2b = (const float*)d_in[7];
    const float* pw1 = (const float*)d_in[8];
    const float* pb1 = (const float*)d_in[9];
    const float* pw2 = (const float*)d_in[10];
    const float* pb2 = (const float*)d_in[11];
    const float* pw3 = (const float*)d_in[12];
    const float* pb3 = (const float*)d_in[13];
    const float* tw1 = (const float*)d_in[14];
    const float* tb1 = (const float*)d_in[15];
    const float* tw2 = (const float*)d_in[16];
    const float* tb2 = (const float*)d_in[17];
    const float* tw3 = (const float*)d_in[18];
    const float* tb3 = (const float*)d_in[19];
    float* out = (float*)d_out;

    const int* src = ei;
    const int* dst = ei + EE;

    // ---- workspace layout ----
    char* base = (char*)d_ws;
    int* cnt = (int*)base;                          // NN ints
    size_t off = (((size_t)NN * 4) + 511) & ~(size_t)511;
    unsigned* pairs = (unsigned*)(base + off);      // NN*CAP uints = 19.2 MB
    float* dis = (float*)(pairs + (size_t)NN * CAP);  // NN
    float* selfn = dis + NN;                        // NN
    float* rdis = selfn + NN;                       // NN
    float* y0 = rdis + NN;                          // NN*3
    float* y1 = y0 + NN * 3;                        // NN*3
    float* y2 = y1 + NN * 3;                        // NN*3
    float* y3 = y2 + NN * 3;                        // NN*3
    float* o2 = y3 + NN * 3;                        // NN*64 f32
    float* pooled = o2 + (size_t)NN * 64;           // GG*64
    float* cntf = pooled + GG * 64;                 // GG
    bf16* hb0 = (bf16*)(cntf + GG);                 // NN*64 bf16 (16B-aligned)
    bf16* hb1 = hb0 + (size_t)NN * 64;
    bf16* hb2 = hb1 + (size_t)NN * 64;
    bf16* hb3 = hb2 + (size_t)NN * 64;

    // ---- init (graph-capture-safe memsets) ----
    hipMemsetAsync(cnt, 0, (size_t)NN * 4, stream);
    hipMemsetAsync(pooled, 0, (size_t)(GG * 64 + GG) * 4, stream);

    // ---- XCD-aligned dst-partitioned bucket CSR build ----
    build_bucket<<<PPART * BPP, 256, 0, stream>>>(src, dst, ew, cnt, pairs);

    // ---- per-node factors + y0 ----
    node_fac<<<392, 256, 0, stream>>>(cnt, pairs, X, dis, selfn, rdis, y0);

    // ---- layer 1 hops (F=3, y-space) ----
    gather3_kernel<<<392, 256, 0, stream>>>(cnt, pairs, selfn, y0, y1);
    gather3_kernel<<<392, 256, 0, stream>>>(cnt, pairs, selfn, y1, y2);
    gather3_kernel<<<392, 256, 0, stream>>>(cnt, pairs, selfn, y2, y3);
    l1_out<<<NN / 32, 256, 0, stream>>>(y0, y1, y2, y3, c1w, c1b, rdis, dis, hb0);

    // ---- layer 2 hops (F=64, bf16 y-space, 2 nodes/wave) ----
    gather64b_kernel<<<12500, 256, 0, stream>>>(cnt, pairs, selfn, hb0, hb1);
    gather64b_kernel<<<12500, 256, 0, stream>>>(cnt, pairs, selfn, hb1, hb2);
    gather64b_kernel<<<12500, 256, 0, stream>>>(cnt, pairs, selfn, hb2, hb3);
    l2_mfma<<<(NN + 63) / 64, 256, 0, stream>>>(hb0, hb1, hb2, hb3, c2w, c2b, rdis, o2);

    // ---- pool + heads ----
    pool_kernel<<<PWAVES / 4, 256, 0, stream>>>(o2, batching, pooled, cntf);
    head_kernel<<<GG, 64, 0, stream>>>(pooled, cntf, pw1, pb1, pw2, pb2, pw3, pb3,
                                       tw1, tb1, tw2, tb2, tw3, tb3, out);
}

// Round 14
// 423.933 us; speedup vs baseline: 1.2166x; 1.2166x over previous
//
#include <hip/hip_runtime.h>
#include <hip/hip_bf16.h>

#define NN 100000
#define EE 1600000
#define GG 256
#define SLOPE 0.01f
#define CAP 48      // bucket capacity; deg~Poisson(16), P(deg>48) ~ 1e-13
#define PPART 8     // dst partitions for build == number of XCDs
#define NPART (NN / PPART)   // 12500 nodes per partition
#define BPP 250              // blocks per partition
#define EPB (EE / BPP)       // 6400 edges per block (exact)

typedef __hip_bfloat16 bf16;
typedef __attribute__((ext_vector_type(8))) short s16x8;
typedef __attribute__((ext_vector_type(4))) float f32x4;

__device__ __forceinline__ float leaky(float x) { return x > 0.f ? x : SLOPE * x; }
__device__ __forceinline__ float bf2f(bf16 v) { return __bfloat162float(v); }
__device__ __forceinline__ float bf_lo(unsigned v) { return __uint_as_float(v << 16); }
__device__ __forceinline__ float bf_hi(unsigned v) { return __uint_as_float(v & 0xFFFF0000u); }

// pack: src (17b) | bf16-weight-sans-sign (15b). w >= 0 always (uniform[0,1)).
__device__ __forceinline__ unsigned pack_pair(int s, float w) {
    unsigned u = __float_as_uint(w);
    u += 0x7FFFu + ((u >> 16) & 1u);  // RNE to bf16
    return ((unsigned)s << 15) | ((u >> 16) & 0x7FFFu);
}
__device__ __forceinline__ int pair_src(unsigned v) { return (int)(v >> 15); }
__device__ __forceinline__ float pair_w(unsigned v) {
    return __uint_as_float((v & 0x7FFFu) << 16);
}

// ---------- dst-partitioned bucket-CSR build, partition pinned to XCD ----------
// partition = blockIdx % 8 pins each partition to ONE XCD (round-robin dispatch);
// nt loads on the edge streams only (read-once by this kernel, filtered 8x).
__global__ __launch_bounds__(256) void build_bucket(const int* __restrict__ src,
                                                    const int* __restrict__ dst,
                                                    const float* __restrict__ ew,
                                                    int* __restrict__ cnt,
                                                    unsigned* __restrict__ pairs) {
    int part = blockIdx.x % PPART;   // XCD-aligned partition
    int blk = blockIdx.x / PPART;
    int lo = part * NPART, hi = lo + NPART;
    int start = blk * EPB;  // EPB = 25 * 256 exactly
#pragma unroll
    for (int jb = 0; jb < 5; jb++) {
        int e[5], d[5];
#pragma unroll
        for (int j = 0; j < 5; j++) {
            e[j] = start + (jb * 5 + j) * 256 + threadIdx.x;
            d[j] = __builtin_nontemporal_load(&dst[e[j]]);
        }
#pragma unroll
        for (int j = 0; j < 5; j++) {
            if (d[j] >= lo && d[j] < hi) {
                int s = __builtin_nontemporal_load(&src[e[j]]);
                float w = __builtin_nontemporal_load(&ew[e[j]]);
                int pos = atomicAdd(&cnt[d[j]], 1);
                if (pos < CAP) pairs[d[j] * CAP + pos] = pack_pair(s, w);
            }
        }
    }
}

// ---------- per-node factors + y0 = dis * X (no atomics) ----------
__global__ void node_fac(const int* __restrict__ cnt, const unsigned* __restrict__ pairs,
                         const float* __restrict__ X, float* __restrict__ dis,
                         float* __restrict__ selfn, float* __restrict__ rdis,
                         float* __restrict__ y0) {
    int n = blockIdx.x * blockDim.x + threadIdx.x;
    if (n >= NN) return;
    int len = min(cnt[n], CAP);
    float deg = 1.0f;  // self-loop weight
    const unsigned* row = pairs + n * CAP;
    for (int i = 0; i < len; i++) deg += pair_w(row[i]);
    float r = rsqrtf(deg);
    dis[n] = r;
    selfn[n] = r * r;       // 1/deg
    rdis[n] = deg * r;      // sqrt(deg) = 1/dis
    y0[n * 3 + 0] = r * X[n * 3 + 0];
    y0[n * 3 + 1] = r * X[n * 3 + 1];
    y0[n * 3 + 2] = r * X[n * 3 + 2];
}

// ---------- propagation F=3 in y-space: y' = selfn*(y[n] + sum w*y[src]) ----------
__global__ void gather3_kernel(const int* __restrict__ cnt, const unsigned* __restrict__ pairs,
                               const float* __restrict__ selfn, const float* __restrict__ yin,
                               float* __restrict__ yout) {
    int n = blockIdx.x * blockDim.x + threadIdx.x;
    if (n >= NN) return;
    int len = min(cnt[n], CAP);
    const unsigned* row = pairs + n * CAP;
    float a0 = yin[n * 3 + 0], a1 = yin[n * 3 + 1], a2 = yin[n * 3 + 2];
    for (int i = 0; i < len; i++) {
        unsigned v = row[i];
        int s3 = pair_src(v) * 3;
        float w = pair_w(v);
        a0 += w * yin[s3 + 0];
        a1 += w * yin[s3 + 1];
        a2 += w * yin[s3 + 2];
    }
    float sv = selfn[n];
    yout[n * 3 + 0] = sv * a0;
    yout[n * 3 + 1] = sv * a1;
    yout[n * 3 + 2] = sv * a2;
}

// ---------- propagation F=64, 4 nodes per wave (16 lanes x 8B per row) ----------
// 32 independent row-gathers in flight per wave (vs 16 at 2-node) for latency hiding.
__global__ __launch_bounds__(256) void gather64b_kernel(const int* __restrict__ cnt,
                                                        const unsigned* __restrict__ pairs,
                                                        const float* __restrict__ selfn,
                                                        const bf16* __restrict__ yin,
                                                        bf16* __restrict__ yout) {
    int wv = (int)((blockIdx.x * (unsigned)blockDim.x + threadIdx.x) >> 6);
    int lane = threadIdx.x & 63;
    int q = lane >> 4, sub = lane & 15;   // node-in-wave, 8B chunk within row
    int node = wv * 4 + q;
    if (node >= NN) return;
    int len = min(cnt[node], CAP);
    const unsigned* row = pairs + node * CAP;
    const uint2* ybase = (const uint2*)yin;  // 4 bf16 per uint2, 16 uint2 per row
    uint2 sv2 = ybase[node * 16 + sub];
    float a0 = bf_lo(sv2.x), a1 = bf_hi(sv2.x);   // self edge, weight 1
    float a2 = bf_lo(sv2.y), a3 = bf_hi(sv2.y);
    int i = 0;
    for (; i + 7 < len; i += 8) {
        unsigned pv[8];
        uint2 gv[8];
#pragma unroll
        for (int j = 0; j < 8; j++) pv[j] = row[i + j];
#pragma unroll
        for (int j = 0; j < 8; j++) gv[j] = ybase[pair_src(pv[j]) * 16 + sub];
#pragma unroll
        for (int j = 0; j < 8; j++) {
            float w = pair_w(pv[j]);
            a0 += w * bf_lo(gv[j].x);
            a1 += w * bf_hi(gv[j].x);
            a2 += w * bf_lo(gv[j].y);
            a3 += w * bf_hi(gv[j].y);
        }
    }
    for (; i < len; i++) {
        unsigned v = row[i];
        uint2 g = ybase[pair_src(v) * 16 + sub];
        float w = pair_w(v);
        a0 += w * bf_lo(g.x);
        a1 += w * bf_hi(g.x);
        a2 += w * bf_lo(g.y);
        a3 += w * bf_hi(g.y);
    }
    float s = selfn[node];
    bf16 b0 = __float2bfloat16(a0 * s), b1 = __float2bfloat16(a1 * s);
    bf16 b2 = __float2bfloat16(a2 * s), b3 = __float2bfloat16(a3 * s);
    uint2 o;
    o.x = ((unsigned)*(unsigned short*)&b1 << 16) | *(unsigned short*)&b0;
    o.y = ((unsigned)*(unsigned short*)&b3 << 16) | *(unsigned short*)&b2;
    ((uint2*)yout)[node * 16 + sub] = o;
}

// ---------- layer 1 output: h = leaky(rdis*sum_k y_k@W_k + b); store dis*h (y-space) ----------
__global__ __launch_bounds__(256) void l1_out(const float* __restrict__ y0, const float* __restrict__ y1,
                                              const float* __restrict__ y2, const float* __restrict__ y3,
                                              const float* __restrict__ w, const float* __restrict__ b,
                                              const float* __restrict__ rdis, const float* __restrict__ dis,
                                              bf16* __restrict__ h) {
    __shared__ float wl[4 * 3 * 64];
    __shared__ float bl[64];
    for (int t = threadIdx.x; t < 768; t += 256) wl[t] = w[t];
    if (threadIdx.x < 64) bl[threadIdx.x] = b[threadIdx.x];
    __syncthreads();
    int lane = threadIdx.x & 63;
    int nodeBase = blockIdx.x * 32 + (threadIdx.x >> 6) * 8;  // N = 3125*32 exactly
    const float* ys[4] = {y0, y1, y2, y3};
#pragma unroll
    for (int r = 0; r < 8; r++) {
        int node = nodeBase + r;
        float acc = 0.f;
#pragma unroll
        for (int k = 0; k < 4; k++) {
            const float* yp = ys[k] + node * 3;
            acc += yp[0] * wl[k * 192 + lane] + yp[1] * wl[k * 192 + 64 + lane] +
                   yp[2] * wl[k * 192 + 128 + lane];
        }
        float hv = leaky(rdis[node] * acc + bl[lane]);
        h[node * 64 + lane] = __float2bfloat16(dis[node] * hv);  // y-space for layer 2
    }
}

// ---------- layer 2 via MFMA (16x16x32 bf16, K=256, N=64), y-space in, bf16 out ----
// A-frag: lane l holds A[l&15][(l>>4)*8 + j]; B-frag: lane l holds B[(l>>4)*8+j][l&15].
// C/D (verified m89): col = lane&15, row = (lane>>4)*4 + reg.
__global__ __launch_bounds__(256) void l2_mfma(const bf16* __restrict__ h0, const bf16* __restrict__ h1,
                                               const bf16* __restrict__ h2, const bf16* __restrict__ h3,
                                               const float* __restrict__ w, const float* __restrict__ b,
                                               const float* __restrict__ rdis, bf16* __restrict__ out) {
    __shared__ bf16 bt[64 * 256];  // BT[n][k], XOR-swizzled, 32 KiB
    __shared__ float bl[64];
    char* btc = (char*)bt;
    for (int idx = threadIdx.x; idx < 16384; idx += 256) {
        int k = idx >> 6, n = idx & 63;  // k = hop*64 + j (row-major w)
        bf16 v = __float2bfloat16(w[idx]);
        *(bf16*)(btc + n * 512 + ((k * 2) ^ ((n & 7) << 4))) = v;
    }
    if (threadIdx.x < 64) bl[threadIdx.x] = b[threadIdx.x];
    __syncthreads();

    int lane = threadIdx.x & 63;
    int rbase = blockIdx.x * 64 + (threadIdx.x >> 6) * 16;  // wave's 16-row tile
    if (rbase >= NN) return;
    const bf16* hs[4] = {h0, h1, h2, h3};

    f32x4 acc0 = {0.f, 0.f, 0.f, 0.f}, acc1 = acc0, acc2 = acc0, acc3 = acc0;
    int arow = rbase + (lane & 15);
    int kgrp = (lane >> 4) * 8;
#pragma unroll
    for (int ks = 0; ks < 8; ks++) {
        const bf16* hp = hs[ks >> 1];
        s16x8 a = *(const s16x8*)(hp + arow * 64 + (ks & 1) * 32 + kgrp);
        int kbyte = ks * 64 + kgrp * 2;
#pragma unroll
        for (int t = 0; t < 4; t++) {
            int n = t * 16 + (lane & 15);
            s16x8 bb = *(const s16x8*)(btc + n * 512 + (kbyte ^ ((n & 7) << 4)));
            f32x4* ap = (t == 0) ? &acc0 : (t == 1) ? &acc1 : (t == 2) ? &acc2 : &acc3;
            *ap = __builtin_amdgcn_mfma_f32_16x16x32_bf16(a, bb, *ap, 0, 0, 0);
        }
    }
    int col = lane & 15, rgrp = (lane >> 4) * 4;
#pragma unroll
    for (int t = 0; t < 4; t++) {
        f32x4 a = (t == 0) ? acc0 : (t == 1) ? acc1 : (t == 2) ? acc2 : acc3;
        float bias = bl[t * 16 + col];
#pragma unroll
        for (int r = 0; r < 4; r++) {
            int rowi = rbase + rgrp + r;
            out[(size_t)rowi * 64 + t * 16 + col] = __float2bfloat16(leaky(rdis[rowi] * a[r] + bias));
        }
    }
}

// ---------- pooling (Batching is sorted; h is bf16) ----------
#define PWAVES 2048
#define NPW ((NN + PWAVES - 1) / PWAVES)  // 49
__global__ void pool_kernel(const bf16* __restrict__ h, const int* __restrict__ batching,
                            float* __restrict__ pooled, float* __restrict__ cnt) {
    int wid = (int)((blockIdx.x * (unsigned)blockDim.x + threadIdx.x) >> 6);
    int lane = threadIdx.x & 63;
    int start = wid * NPW;
    if (start >= NN) return;
    int end = min(start + NPW, NN);
    int g = batching[start];
    float acc = 0.f, c = 0.f;
    for (int i = start; i < end; i++) {
        int gi = batching[i];
        if (gi != g) {
            atomicAdd(&pooled[g * 64 + lane], acc);
            if (lane == 0) atomicAdd(&cnt[g], c);
            g = gi; acc = 0.f; c = 0.f;
        }
        acc += bf2f(h[(size_t)i * 64 + lane]);
        c += 1.f;
    }
    atomicAdd(&pooled[g * 64 + lane], acc);
    if (lane == 0) atomicAdd(&cnt[g], c);
}

// ---------- heads: two 64->64->64->2 MLPs per graph ----------
__global__ void head_kernel(const float* __restrict__ pooled, const float* __restrict__ cnt,
                            const float* pw1, const float* pb1, const float* pw2, const float* pb2,
                            const float* pw3, const float* pb3,
                            const float* tw1, const float* tb1, const float* tw2, const float* tb2,
                            const float* tw3, const float* tb3,
                            float* __restrict__ out) {
    int g = blockIdx.x, f = threadIdx.x;  // 64 threads
    __shared__ float pm[64], t1[64], t2[64];
    float c = cnt[g];
    if (c < 1.f) c = 1.f;
    pm[f] = pooled[g * 64 + f] / c;
    __syncthreads();
    float a = pb1[f];
    for (int j = 0; j < 64; j++) a += pm[j] * pw1[j * 64 + f];
    t1[f] = leaky(a);
    __syncthreads();
    a = pb2[f];
    for (int j = 0; j < 64; j++) a += t1[j] * pw2[j * 64 + f];
    t2[f] = leaky(a);
    __syncthreads();
    if (f < 2) {
        float o = pb3[f];
        for (int j = 0; j < 64; j++) o += t2[j] * pw3[j * 2 + f];
        out[g * 4 + f] = o;
    }
    __syncthreads();
    a = tb1[f];
    for (int j = 0; j < 64; j++) a += pm[j] * tw1[j * 64 + f];
    t1[f] = leaky(a);
    __syncthreads();
    a = tb2[f];
    for (int j = 0; j < 64; j++) a += t1[j] * tw2[j * 64 + f];
    t2[f] = leaky(a);
    __syncthreads();
    if (f < 2) {
        float o = tb3[f];
        for (int j = 0; j < 64; j++) o += t2[j] * tw3[j * 2 + f];
        out[g * 4 + 2 + f] = o;
    }
}

extern "C" void kernel_launch(void* const* d_in, const int* in_sizes, int n_in,
                              void* d_out, int out_size, void* d_ws, size_t ws_size,
                              hipStream_t stream) {
    const float* X = (const float*)d_in[0];
    const int* ei = (const int*)d_in[1];  // [2][E]
    const float* ew = (const float*)d_in[2];
    const int* batching = (const int*)d_in[3];
    const float* c1w = (const float*)d_in[4];
    const float* c1b = (const float*)d_in[5];
    const float* c2w = (const float*)d_in[6];
    const float* c2b = (const float*)d_in[7];
    const float* pw1 = (const float*)d_in[8];
    const float* pb1 = (const float*)d_in[9];
    const float* pw2 = (const float*)d_in[10];
    const float* pb2 = (const float*)d_in[11];
    const float* pw3 = (const float*)d_in[12];
    const float* pb3 = (const float*)d_in[13];
    const float* tw1 = (const float*)d_in[14];
    const float* tb1 = (const float*)d_in[15];
    const float* tw2 = (const float*)d_in[16];
    const float* tb2 = (const float*)d_in[17];
    const float* tw3 = (const float*)d_in[18];
    const float* tb3 = (const float*)d_in[19];
    float* out = (float*)d_out;

    const int* src = ei;
    const int* dst = ei + EE;

    // ---- workspace layout ----
    char* base = (char*)d_ws;
    int* cnt = (int*)base;                          // NN ints
    size_t off = (((size_t)NN * 4) + 511) & ~(size_t)511;
    unsigned* pairs = (unsigned*)(base + off);      // NN*CAP uints = 19.2 MB
    float* dis = (float*)(pairs + (size_t)NN * CAP);  // NN
    float* selfn = dis + NN;                        // NN
    float* rdis = selfn + NN;                       // NN
    float* y0 = rdis + NN;                          // NN*3
    float* y1 = y0 + NN * 3;                        // NN*3
    float* y2 = y1 + NN * 3;                        // NN*3
    float* y3 = y2 + NN * 3;                        // NN*3
    float* pooled = y3 + NN * 3;                    // GG*64
    float* cntf = pooled + GG * 64;                 // GG
    bf16* hb0 = (bf16*)(cntf + GG);                 // NN*64 bf16 (16B-aligned)
    bf16* hb1 = hb0 + (size_t)NN * 64;
    bf16* hb2 = hb1 + (size_t)NN * 64;
    bf16* hb3 = hb2 + (size_t)NN * 64;
    bf16* o2 = hb3 + (size_t)NN * 64;               // NN*64 bf16

    // ---- init (graph-capture-safe memsets) ----
    hipMemsetAsync(cnt, 0, (size_t)NN * 4, stream);
    hipMemsetAsync(pooled, 0, (size_t)(GG * 64 + GG) * 4, stream);

    // ---- XCD-aligned dst-partitioned bucket CSR build ----
    build_bucket<<<PPART * BPP, 256, 0, stream>>>(src, dst, ew, cnt, pairs);

    // ---- per-node factors + y0 ----
    node_fac<<<392, 256, 0, stream>>>(cnt, pairs, X, dis, selfn, rdis, y0);

    // ---- layer 1 hops (F=3, y-space) ----
    gather3_kernel<<<392, 256, 0, stream>>>(cnt, pairs, selfn, y0, y1);
    gather3_kernel<<<392, 256, 0, stream>>>(cnt, pairs, selfn, y1, y2);
    gather3_kernel<<<392, 256, 0, stream>>>(cnt, pairs, selfn, y2, y3);
    l1_out<<<NN / 32, 256, 0, stream>>>(y0, y1, y2, y3, c1w, c1b, rdis, dis, hb0);

    // ---- layer 2 hops (F=64, bf16 y-space, 4 nodes/wave) ----
    gather64b_kernel<<<6250, 256, 0, stream>>>(cnt, pairs, selfn, hb0, hb1);
    gather64b_kernel<<<6250, 256, 0, stream>>>(cnt, pairs, selfn, hb1, hb2);
    gather64b_kernel<<<6250, 256, 0, stream>>>(cnt, pairs, selfn, hb2, hb3);
    l2_mfma<<<(NN + 63) / 64, 256, 0, stream>>>(hb0, hb1, hb2, hb3, c2w, c2b, rdis, o2);

    // ---- pool + heads ----
    pool_kernel<<<PWAVES / 4, 256, 0, stream>>>(o2, batching, pooled, cntf);
    head_kernel<<<GG, 64, 0, stream>>>(pooled, cntf, pw1, pb1, pw2, pb2, pw3, pb3,
                                       tw1, tb1, tw2, tb2, tw3, tb3, out);
}

// Round 15
// 422.748 us; speedup vs baseline: 1.2200x; 1.0028x over previous
//
#include <hip/hip_runtime.h>
#include <hip/hip_bf16.h>

#define NN 100000
#define EE 1600000
#define GG 256
#define SLOPE 0.01f
#define CAP 48      // bucket capacity; deg~Poisson(16), P(deg>48) ~ 1e-13
#define PPART 8     // dst partitions for build == number of XCDs
#define NPART (NN / PPART)   // 12500 nodes per partition
#define BPP 250              // blocks per partition
#define EPB (EE / BPP)       // 6400 edges per block (exact)

typedef __hip_bfloat16 bf16;
typedef __attribute__((ext_vector_type(8))) short s16x8;
typedef __attribute__((ext_vector_type(4))) float f32x4;

__device__ __forceinline__ float leaky(float x) { return x > 0.f ? x : SLOPE * x; }
__device__ __forceinline__ float bf2f(bf16 v) { return __bfloat162float(v); }
__device__ __forceinline__ float bf_lo(unsigned v) { return __uint_as_float(v << 16); }
__device__ __forceinline__ float bf_hi(unsigned v) { return __uint_as_float(v & 0xFFFF0000u); }

// pack: src (17b) | bf16-weight-sans-sign (15b). w >= 0 always (uniform[0,1)).
__device__ __forceinline__ unsigned pack_pair(int s, float w) {
    unsigned u = __float_as_uint(w);
    u += 0x7FFFu + ((u >> 16) & 1u);  // RNE to bf16
    return ((unsigned)s << 15) | ((u >> 16) & 0x7FFFu);
}
__device__ __forceinline__ int pair_src(unsigned v) { return (int)(v >> 15); }
__device__ __forceinline__ float pair_w(unsigned v) {
    return __uint_as_float((v & 0x7FFFu) << 16);
}

// ---------- dst-partitioned bucket-CSR build, partition pinned to XCD ----------
__global__ __launch_bounds__(256) void build_bucket(const int* __restrict__ src,
                                                    const int* __restrict__ dst,
                                                    const float* __restrict__ ew,
                                                    int* __restrict__ cnt,
                                                    unsigned* __restrict__ pairs) {
    int part = blockIdx.x % PPART;   // XCD-aligned partition
    int blk = blockIdx.x / PPART;
    int lo = part * NPART, hi = lo + NPART;
    int start = blk * EPB;  // EPB = 25 * 256 exactly
#pragma unroll
    for (int jb = 0; jb < 5; jb++) {
        int e[5], d[5];
#pragma unroll
        for (int j = 0; j < 5; j++) {
            e[j] = start + (jb * 5 + j) * 256 + threadIdx.x;
            d[j] = __builtin_nontemporal_load(&dst[e[j]]);
        }
#pragma unroll
        for (int j = 0; j < 5; j++) {
            if (d[j] >= lo && d[j] < hi) {
                int s = __builtin_nontemporal_load(&src[e[j]]);
                float w = __builtin_nontemporal_load(&ew[e[j]]);
                int pos = atomicAdd(&cnt[d[j]], 1);
                if (pos < CAP) pairs[d[j] * CAP + pos] = pack_pair(s, w);
            }
        }
    }
}

// ---------- per-node factors + y0 = dis * X (no atomics) ----------
__global__ void node_fac(const int* __restrict__ cnt, const unsigned* __restrict__ pairs,
                         const float* __restrict__ X, float* __restrict__ dis,
                         float* __restrict__ selfn, float* __restrict__ rdis,
                         float* __restrict__ y0) {
    int n = blockIdx.x * blockDim.x + threadIdx.x;
    if (n >= NN) return;
    int len = min(cnt[n], CAP);
    float deg = 1.0f;  // self-loop weight
    const unsigned* row = pairs + n * CAP;
    for (int i = 0; i < len; i++) deg += pair_w(row[i]);
    float r = rsqrtf(deg);
    dis[n] = r;
    selfn[n] = r * r;       // 1/deg
    rdis[n] = deg * r;      // sqrt(deg) = 1/dis
    y0[n * 3 + 0] = r * X[n * 3 + 0];
    y0[n * 3 + 1] = r * X[n * 3 + 1];
    y0[n * 3 + 2] = r * X[n * 3 + 2];
}

// ---------- propagation F=3 in y-space: y' = selfn*(y[n] + sum w*y[src]) ----------
__global__ void gather3_kernel(const int* __restrict__ cnt, const unsigned* __restrict__ pairs,
                               const float* __restrict__ selfn, const float* __restrict__ yin,
                               float* __restrict__ yout) {
    int n = blockIdx.x * blockDim.x + threadIdx.x;
    if (n >= NN) return;
    int len = min(cnt[n], CAP);
    const unsigned* row = pairs + n * CAP;
    float a0 = yin[n * 3 + 0], a1 = yin[n * 3 + 1], a2 = yin[n * 3 + 2];
    for (int i = 0; i < len; i++) {
        unsigned v = row[i];
        int s3 = pair_src(v) * 3;
        float w = pair_w(v);
        a0 += w * yin[s3 + 0];
        a1 += w * yin[s3 + 1];
        a2 += w * yin[s3 + 2];
    }
    float sv = selfn[n];
    yout[n * 3 + 0] = sv * a0;
    yout[n * 3 + 1] = sv * a1;
    yout[n * 3 + 2] = sv * a2;
}

// ---------- propagation F=64, 8 nodes per wave (8 lanes x 16B per row) ----------
// 64 independent row-gathers in flight per wave (vs 32 at 4-node) for latency hiding.
__global__ __launch_bounds__(256) void gather64b_kernel(const int* __restrict__ cnt,
                                                        const unsigned* __restrict__ pairs,
                                                        const float* __restrict__ selfn,
                                                        const bf16* __restrict__ yin,
                                                        bf16* __restrict__ yout) {
    int wv = (int)((blockIdx.x * (unsigned)blockDim.x + threadIdx.x) >> 6);
    int lane = threadIdx.x & 63;
    int q = lane >> 3, sub = lane & 7;   // node-in-wave (0..7), 16B chunk within row
    int node = wv * 8 + q;
    if (node >= NN) return;
    int len = min(cnt[node], CAP);
    const unsigned* row = pairs + node * CAP;
    const uint4* ybase = (const uint4*)yin;  // 8 bf16 per uint4, 8 uint4 per row
    uint4 sv4 = ybase[node * 8 + sub];
    float a0 = bf_lo(sv4.x), a1 = bf_hi(sv4.x);   // self edge, weight 1
    float a2 = bf_lo(sv4.y), a3 = bf_hi(sv4.y);
    float a4 = bf_lo(sv4.z), a5 = bf_hi(sv4.z);
    float a6 = bf_lo(sv4.w), a7 = bf_hi(sv4.w);
    int i = 0;
    for (; i + 7 < len; i += 8) {
        unsigned pv[8];
        uint4 gv[8];
#pragma unroll
        for (int j = 0; j < 8; j++) pv[j] = row[i + j];
#pragma unroll
        for (int j = 0; j < 8; j++) gv[j] = ybase[pair_src(pv[j]) * 8 + sub];
#pragma unroll
        for (int j = 0; j < 8; j++) {
            float w = pair_w(pv[j]);
            a0 += w * bf_lo(gv[j].x);
            a1 += w * bf_hi(gv[j].x);
            a2 += w * bf_lo(gv[j].y);
            a3 += w * bf_hi(gv[j].y);
            a4 += w * bf_lo(gv[j].z);
            a5 += w * bf_hi(gv[j].z);
            a6 += w * bf_lo(gv[j].w);
            a7 += w * bf_hi(gv[j].w);
        }
    }
    for (; i < len; i++) {
        unsigned v = row[i];
        uint4 g = ybase[pair_src(v) * 8 + sub];
        float w = pair_w(v);
        a0 += w * bf_lo(g.x);
        a1 += w * bf_hi(g.x);
        a2 += w * bf_lo(g.y);
        a3 += w * bf_hi(g.y);
        a4 += w * bf_lo(g.z);
        a5 += w * bf_hi(g.z);
        a6 += w * bf_lo(g.w);
        a7 += w * bf_hi(g.w);
    }
    float s = selfn[node];
    bf16 b0 = __float2bfloat16(a0 * s), b1 = __float2bfloat16(a1 * s);
    bf16 b2 = __float2bfloat16(a2 * s), b3 = __float2bfloat16(a3 * s);
    bf16 b4 = __float2bfloat16(a4 * s), b5 = __float2bfloat16(a5 * s);
    bf16 b6 = __float2bfloat16(a6 * s), b7 = __float2bfloat16(a7 * s);
    uint4 o;
    o.x = ((unsigned)*(unsigned short*)&b1 << 16) | *(unsigned short*)&b0;
    o.y = ((unsigned)*(unsigned short*)&b3 << 16) | *(unsigned short*)&b2;
    o.z = ((unsigned)*(unsigned short*)&b5 << 16) | *(unsigned short*)&b4;
    o.w = ((unsigned)*(unsigned short*)&b7 << 16) | *(unsigned short*)&b6;
    ((uint4*)yout)[node * 8 + sub] = o;
}

// ---------- layer 1 output: h = leaky(rdis*sum_k y_k@W_k + b); store dis*h (y-space) ----------
__global__ __launch_bounds__(256) void l1_out(const float* __restrict__ y0, const float* __restrict__ y1,
                                              const float* __restrict__ y2, const float* __restrict__ y3,
                                              const float* __restrict__ w, const float* __restrict__ b,
                                              const float* __restrict__ rdis, const float* __restrict__ dis,
                                              bf16* __restrict__ h) {
    __shared__ float wl[4 * 3 * 64];
    __shared__ float bl[64];
    for (int t = threadIdx.x; t < 768; t += 256) wl[t] = w[t];
    if (threadIdx.x < 64) bl[threadIdx.x] = b[threadIdx.x];
    __syncthreads();
    int lane = threadIdx.x & 63;
    int nodeBase = blockIdx.x * 32 + (threadIdx.x >> 6) * 8;  // N = 3125*32 exactly
    const float* ys[4] = {y0, y1, y2, y3};
#pragma unroll
    for (int r = 0; r < 8; r++) {
        int node = nodeBase + r;
        float acc = 0.f;
#pragma unroll
        for (int k = 0; k < 4; k++) {
            const float* yp = ys[k] + node * 3;
            acc += yp[0] * wl[k * 192 + lane] + yp[1] * wl[k * 192 + 64 + lane] +
                   yp[2] * wl[k * 192 + 128 + lane];
        }
        float hv = leaky(rdis[node] * acc + bl[lane]);
        h[node * 64 + lane] = __float2bfloat16(dis[node] * hv);  // y-space for layer 2
    }
}

// ---------- layer 2 via MFMA (16x16x32 bf16, K=256, N=64), y-space in, bf16 out ----
// A-frag: lane l holds A[l&15][(l>>4)*8 + j]; B-frag: lane l holds B[(l>>4)*8+j][l&15].
// C/D (verified m89): col = lane&15, row = (lane>>4)*4 + reg.
__global__ __launch_bounds__(256) void l2_mfma(const bf16* __restrict__ h0, const bf16* __restrict__ h1,
                                               const bf16* __restrict__ h2, const bf16* __restrict__ h3,
                                               const float* __restrict__ w, const float* __restrict__ b,
                                               const float* __restrict__ rdis, bf16* __restrict__ out) {
    __shared__ bf16 bt[64 * 256];  // BT[n][k], XOR-swizzled, 32 KiB
    __shared__ float bl[64];
    char* btc = (char*)bt;
    for (int idx = threadIdx.x; idx < 16384; idx += 256) {
        int k = idx >> 6, n = idx & 63;  // k = hop*64 + j (row-major w)
        bf16 v = __float2bfloat16(w[idx]);
        *(bf16*)(btc + n * 512 + ((k * 2) ^ ((n & 7) << 4))) = v;
    }
    if (threadIdx.x < 64) bl[threadIdx.x] = b[threadIdx.x];
    __syncthreads();

    int lane = threadIdx.x & 63;
    int rbase = blockIdx.x * 64 + (threadIdx.x >> 6) * 16;  // wave's 16-row tile
    if (rbase >= NN) return;
    const bf16* hs[4] = {h0, h1, h2, h3};

    f32x4 acc0 = {0.f, 0.f, 0.f, 0.f}, acc1 = acc0, acc2 = acc0, acc3 = acc0;
    int arow = rbase + (lane & 15);
    int kgrp = (lane >> 4) * 8;
#pragma unroll
    for (int ks = 0; ks < 8; ks++) {
        const bf16* hp = hs[ks >> 1];
        s16x8 a = *(const s16x8*)(hp + arow * 64 + (ks & 1) * 32 + kgrp);
        int kbyte = ks * 64 + kgrp * 2;
#pragma unroll
        for (int t = 0; t < 4; t++) {
            int n = t * 16 + (lane & 15);
            s16x8 bb = *(const s16x8*)(btc + n * 512 + (kbyte ^ ((n & 7) << 4)));
            f32x4* ap = (t == 0) ? &acc0 : (t == 1) ? &acc1 : (t == 2) ? &acc2 : &acc3;
            *ap = __builtin_amdgcn_mfma_f32_16x16x32_bf16(a, bb, *ap, 0, 0, 0);
        }
    }
    int col = lane & 15, rgrp = (lane >> 4) * 4;
#pragma unroll
    for (int t = 0; t < 4; t++) {
        f32x4 a = (t == 0) ? acc0 : (t == 1) ? acc1 : (t == 2) ? acc2 : acc3;
        float bias = bl[t * 16 + col];
#pragma unroll
        for (int r = 0; r < 4; r++) {
            int rowi = rbase + rgrp + r;
            out[(size_t)rowi * 64 + t * 16 + col] = __float2bfloat16(leaky(rdis[rowi] * a[r] + bias));
        }
    }
}

// ---------- pooling (Batching is sorted; h is bf16) ----------
#define PWAVES 2048
#define NPW ((NN + PWAVES - 1) / PWAVES)  // 49
__global__ void pool_kernel(const bf16* __restrict__ h, const int* __restrict__ batching,
                            float* __restrict__ pooled, float* __restrict__ cnt) {
    int wid = (int)((blockIdx.x * (unsigned)blockDim.x + threadIdx.x) >> 6);
    int lane = threadIdx.x & 63;
    int start = wid * NPW;
    if (start >= NN) return;
    int end = min(start + NPW, NN);
    int g = batching[start];
    float acc = 0.f, c = 0.f;
    for (int i = start; i < end; i++) {
        int gi = batching[i];
        if (gi != g) {
            atomicAdd(&pooled[g * 64 + lane], acc);
            if (lane == 0) atomicAdd(&cnt[g], c);
            g = gi; acc = 0.f; c = 0.f;
        }
        acc += bf2f(h[(size_t)i * 64 + lane]);
        c += 1.f;
    }
    atomicAdd(&pooled[g * 64 + lane], acc);
    if (lane == 0) atomicAdd(&cnt[g], c);
}

// ---------- heads: two 64->64->64->2 MLPs per graph ----------
__global__ void head_kernel(const float* __restrict__ pooled, const float* __restrict__ cnt,
                            const float* pw1, const float* pb1, const float* pw2, const float* pb2,
                            const float* pw3, const float* pb3,
                            const float* tw1, const float* tb1, const float* tw2, const float* tb2,
                            const float* tw3, const float* tb3,
                            float* __restrict__ out) {
    int g = blockIdx.x, f = threadIdx.x;  // 64 threads
    __shared__ float pm[64], t1[64], t2[64];
    float c = cnt[g];
    if (c < 1.f) c = 1.f;
    pm[f] = pooled[g * 64 + f] / c;
    __syncthreads();
    float a = pb1[f];
    for (int j = 0; j < 64; j++) a += pm[j] * pw1[j * 64 + f];
    t1[f] = leaky(a);
    __syncthreads();
    a = pb2[f];
    for (int j = 0; j < 64; j++) a += t1[j] * pw2[j * 64 + f];
    t2[f] = leaky(a);
    __syncthreads();
    if (f < 2) {
        float o = pb3[f];
        for (int j = 0; j < 64; j++) o += t2[j] * pw3[j * 2 + f];
        out[g * 4 + f] = o;
    }
    __syncthreads();
    a = tb1[f];
    for (int j = 0; j < 64; j++) a += pm[j] * tw1[j * 64 + f];
    t1[f] = leaky(a);
    __syncthreads();
    a = tb2[f];
    for (int j = 0; j < 64; j++) a += t1[j] * tw2[j * 64 + f];
    t2[f] = leaky(a);
    __syncthreads();
    if (f < 2) {
        float o = tb3[f];
        for (int j = 0; j < 64; j++) o += t2[j] * tw3[j * 2 + f];
        out[g * 4 + 2 + f] = o;
    }
}

extern "C" void kernel_launch(void* const* d_in, const int* in_sizes, int n_in,
                              void* d_out, int out_size, void* d_ws, size_t ws_size,
                              hipStream_t stream) {
    const float* X = (const float*)d_in[0];
    const int* ei = (const int*)d_in[1];  // [2][E]
    const float* ew = (const float*)d_in[2];
    const int* batching = (const int*)d_in[3];
    const float* c1w = (const float*)d_in[4];
    const float* c1b = (const float*)d_in[5];
    const float* c2w = (const float*)d_in[6];
    const float* c2b = (const float*)d_in[7];
    const float* pw1 = (const float*)d_in[8];
    const float* pb1 = (const float*)d_in[9];
    const float* pw2 = (const float*)d_in[10];
    const float* pb2 = (const float*)d_in[11];
    const float* pw3 = (const float*)d_in[12];
    const float* pb3 = (const float*)d_in[13];
    const float* tw1 = (const float*)d_in[14];
    const float* tb1 = (const float*)d_in[15];
    const float* tw2 = (const float*)d_in[16];
    const float* tb2 = (const float*)d_in[17];
    const float* tw3 = (const float*)d_in[18];
    const float* tb3 = (const float*)d_in[19];
    float* out = (float*)d_out;

    const int* src = ei;
    const int* dst = ei + EE;

    // ---- workspace layout ----
    char* base = (char*)d_ws;
    int* cnt = (int*)base;                          // NN ints
    size_t off = (((size_t)NN * 4) + 511) & ~(size_t)511;
    unsigned* pairs = (unsigned*)(base + off);      // NN*CAP uints = 19.2 MB
    float* dis = (float*)(pairs + (size_t)NN * CAP);  // NN
    float* selfn = dis + NN;                        // NN
    float* rdis = selfn + NN;                       // NN
    float* y0 = rdis + NN;                          // NN*3
    float* y1 = y0 + NN * 3;                        // NN*3
    float* y2 = y1 + NN * 3;                        // NN*3
    float* y3 = y2 + NN * 3;                        // NN*3
    float* pooled = y3 + NN * 3;                    // GG*64
    float* cntf = pooled + GG * 64;                 // GG
    bf16* hb0 = (bf16*)(cntf + GG);                 // NN*64 bf16 (16B-aligned)
    bf16* hb1 = hb0 + (size_t)NN * 64;
    bf16* hb2 = hb1 + (size_t)NN * 64;
    bf16* hb3 = hb2 + (size_t)NN * 64;
    bf16* o2 = hb3 + (size_t)NN * 64;               // NN*64 bf16

    // ---- init (graph-capture-safe memsets) ----
    hipMemsetAsync(cnt, 0, (size_t)NN * 4, stream);
    hipMemsetAsync(pooled, 0, (size_t)(GG * 64 + GG) * 4, stream);

    // ---- XCD-aligned dst-partitioned bucket CSR build ----
    build_bucket<<<PPART * BPP, 256, 0, stream>>>(src, dst, ew, cnt, pairs);

    // ---- per-node factors + y0 ----
    node_fac<<<392, 256, 0, stream>>>(cnt, pairs, X, dis, selfn, rdis, y0);

    // ---- layer 1 hops (F=3, y-space) ----
    gather3_kernel<<<392, 256, 0, stream>>>(cnt, pairs, selfn, y0, y1);
    gather3_kernel<<<392, 256, 0, stream>>>(cnt, pairs, selfn, y1, y2);
    gather3_kernel<<<392, 256, 0, stream>>>(cnt, pairs, selfn, y2, y3);
    l1_out<<<NN / 32, 256, 0, stream>>>(y0, y1, y2, y3, c1w, c1b, rdis, dis, hb0);

    // ---- layer 2 hops (F=64, bf16 y-space, 8 nodes/wave) ----
    gather64b_kernel<<<3125, 256, 0, stream>>>(cnt, pairs, selfn, hb0, hb1);
    gather64b_kernel<<<3125, 256, 0, stream>>>(cnt, pairs, selfn, hb1, hb2);
    gather64b_kernel<<<3125, 256, 0, stream>>>(cnt, pairs, selfn, hb2, hb3);
    l2_mfma<<<(NN + 63) / 64, 256, 0, stream>>>(hb0, hb1, hb2, hb3, c2w, c2b, rdis, o2);

    // ---- pool + heads ----
    pool_kernel<<<PWAVES / 4, 256, 0, stream>>>(o2, batching, pooled, cntf);
    head_kernel<<<GG, 64, 0, stream>>>(pooled, cntf, pw1, pb1, pw2, pb2, pw3, pb3,
                                       tw1, tb1, tw2, tb2, tw3, tb3, out);
}